// Round 1
// baseline (1053.342 us; speedup 1.0000x reference)
//
#include <hip/hip_runtime.h>
#include <hip/hip_bf16.h>
#include <stdint.h>

#define ALPHA_ 1.702f
#define FLIMIT 7.0f

constexpr int E_ = 8;
constexpr int H_ = 2048;
constexpr int I_ = 2048;
constexpr int T_ = 2048;

typedef __attribute__((ext_vector_type(8))) short short8;
typedef __attribute__((ext_vector_type(4))) short short4v;
typedef __attribute__((ext_vector_type(4))) float float4v;

__device__ __forceinline__ unsigned short f2bf(float f) {
  union { float f; uint32_t u; } v; v.f = f;
  uint32_t u = v.u;
  uint32_t r = (u + 0x7fffu + ((u >> 16) & 1u)) >> 16;
  return (unsigned short)r;
}

// async global->LDS, 16B per lane. LDS dest must be wave-uniform base + lane*16.
__device__ __forceinline__ void gll16(const void* g, void* l) {
  __builtin_amdgcn_global_load_lds(
      (const __attribute__((address_space(1))) void*)g,
      (__attribute__((address_space(3))) void*)l, 16, 0, 0);
}

// ---------------- conversion kernels ----------------

__global__ void k_cvt_hidden(const float* __restrict__ src, unsigned short* __restrict__ dst) {
  const int i = blockIdx.x * 256 + threadIdx.x;   // grid sized exactly: T*H/4 threads
  const float4v v = ((const float4v*)src)[i];
  short4v o;
  o.x = (short)f2bf(v.x); o.y = (short)f2bf(v.y);
  o.z = (short)f2bf(v.z); o.w = (short)f2bf(v.w);
  ((short4v*)dst)[i] = o;
}

// gate_up_proj [E][H][2I] fp32 -> wg[E][I][H], wu[E][I][H] bf16 (de-interleave + transpose)
__global__ void k_cvt_gateup(const float* __restrict__ w,
                             unsigned short* __restrict__ wg,
                             unsigned short* __restrict__ wu) {
  const int e = blockIdx.z, it = blockIdx.x, ht = blockIdx.y;
  const float* wb = w + (size_t)e * H_ * 2 * I_ + (size_t)(ht * 64) * (2 * I_) + it * 128;
  __shared__ unsigned short lg[64][65], lu[64][65];
  const int tid = threadIdx.x;
#pragma unroll
  for (int ii = 0; ii < 8; ++ii) {
    const int c = tid + ii * 256;            // 2048 float4 chunks: 64 rows x 32
    const int r = c >> 5, q = c & 31;
    const float4v v = *(const float4v*)(wb + (size_t)r * (2 * I_) + q * 4);
    lg[r][q * 2]     = f2bf(v.x);
    lu[r][q * 2]     = f2bf(v.y);
    lg[r][q * 2 + 1] = f2bf(v.z);
    lu[r][q * 2 + 1] = f2bf(v.w);
  }
  __syncthreads();
  unsigned short* og = wg + ((size_t)e * I_ + it * 64) * H_ + ht * 64;
  unsigned short* ou = wu + ((size_t)e * I_ + it * 64) * H_ + ht * 64;
#pragma unroll
  for (int ii = 0; ii < 4; ++ii) {
    const int c = tid + ii * 256;            // 1024: 64 i x 16 h-quads
    const int i = c >> 4, hq = (c & 15) * 4;
    short4v g, u;
    g.x = (short)lg[hq][i];     g.y = (short)lg[hq + 1][i];
    g.z = (short)lg[hq + 2][i]; g.w = (short)lg[hq + 3][i];
    u.x = (short)lu[hq][i];     u.y = (short)lu[hq + 1][i];
    u.z = (short)lu[hq + 2][i]; u.w = (short)lu[hq + 3][i];
    *(short4v*)(og + (size_t)i * H_ + hq) = g;
    *(short4v*)(ou + (size_t)i * H_ + hq) = u;
  }
}

// down_proj [E][I][H] fp32 -> dt[E][H][I] bf16 (transpose)
__global__ void k_cvt_down(const float* __restrict__ w, unsigned short* __restrict__ dt) {
  const int e = blockIdx.z, ht = blockIdx.x, it = blockIdx.y;
  const float* wb = w + ((size_t)e * I_ + it * 64) * H_ + ht * 64;
  __shared__ unsigned short ld[64][65];
  const int tid = threadIdx.x;
#pragma unroll
  for (int ii = 0; ii < 4; ++ii) {
    const int c = tid + ii * 256;            // 1024: 64 i-rows x 16 h-quads
    const int r = c >> 4, q = c & 15;
    const float4v v = *(const float4v*)(wb + (size_t)r * H_ + q * 4);
    ld[r][q * 4]     = f2bf(v.x);
    ld[r][q * 4 + 1] = f2bf(v.y);
    ld[r][q * 4 + 2] = f2bf(v.z);
    ld[r][q * 4 + 3] = f2bf(v.w);
  }
  __syncthreads();
  unsigned short* od = dt + ((size_t)e * H_ + ht * 64) * I_ + it * 64;
#pragma unroll
  for (int ii = 0; ii < 4; ++ii) {
    const int c = tid + ii * 256;            // 64 h x 16 i-quads
    const int h = c >> 4, iq = (c & 15) * 4;
    short4v o;
    o.x = (short)ld[iq][h];     o.y = (short)ld[iq + 1][h];
    o.z = (short)ld[iq + 2][h]; o.w = (short)ld[iq + 3][h];
    *(short4v*)(od + (size_t)h * I_ + iq) = o;
  }
}

// ---------------- GEMM1: gu = hidden @ [Wg|Wu] + bias, activation -> inter ----------------

__global__ __launch_bounds__(256, 2) void k_gemm1(
    const unsigned short* __restrict__ A,    // hidden bf16 [T][H]
    const unsigned short* __restrict__ Bg,   // wg [E][I][H]  (B^T layout)
    const unsigned short* __restrict__ Bu,   // wu [E][I][H]
    const float* __restrict__ gubias,        // [E][2I]
    unsigned short* __restrict__ inter)      // [E][T][I] bf16
{
  const int e  = blockIdx.z;
  const int t0 = blockIdx.y * 128;
  const int i0 = blockIdx.x * 128;

  __shared__ unsigned short sA[2][128 * 32];
  __shared__ unsigned short sG[2][128 * 32];
  __shared__ unsigned short sU[2][128 * 32];

  const int tid  = threadIdx.x;
  const int wid  = tid >> 6;
  const int lane = tid & 63;
  const int wm   = wid >> 1;
  const int wn   = wid & 1;
  const int lr   = lane & 15;
  const int lq   = lane >> 4;
  const int kch  = lq * 8;

  const unsigned short* ga = A  + (size_t)t0 * H_;
  const unsigned short* gg = Bg + ((size_t)e * I_ + i0) * H_;
  const unsigned short* gu = Bu + ((size_t)e * I_ + i0) * H_;

  float4v accg[4][4] = {};
  float4v accu[4][4] = {};

  auto stage = [&](int buf, int kt) {
    const int k0 = kt * 32;
#pragma unroll
    for (int it = 0; it < 2; ++it) {
      const int c = tid + it * 256;          // 512 chunks of 16B per matrix
      const int r = c >> 2;
      const size_t go = (size_t)r * H_ + (k0 + (c & 3) * 8);
      gll16(ga + go, &sA[buf][c * 8]);
      gll16(gg + go, &sG[buf][c * 8]);
      gll16(gu + go, &sU[buf][c * 8]);
    }
  };

  stage(0, 0);
  int cur = 0;
#pragma unroll 1
  for (int kt = 0; kt < 64; ++kt) {
    __syncthreads();                          // drains vmcnt -> staged buf ready
    if (kt + 1 < 64) stage(cur ^ 1, kt + 1);
    short8 a[4], bg[4], bu[4];
#pragma unroll
    for (int m = 0; m < 4; ++m)
      a[m] = *(const short8*)&sA[cur][(wm * 64 + m * 16 + lr) * 32 + kch];
#pragma unroll
    for (int n = 0; n < 4; ++n) {
      bg[n] = *(const short8*)&sG[cur][(wn * 64 + n * 16 + lr) * 32 + kch];
      bu[n] = *(const short8*)&sU[cur][(wn * 64 + n * 16 + lr) * 32 + kch];
    }
#pragma unroll
    for (int m = 0; m < 4; ++m)
#pragma unroll
      for (int n = 0; n < 4; ++n) {
        accg[m][n] = __builtin_amdgcn_mfma_f32_16x16x32_bf16(a[m], bg[n], accg[m][n], 0, 0, 0);
        accu[m][n] = __builtin_amdgcn_mfma_f32_16x16x32_bf16(a[m], bu[n], accu[m][n], 0, 0, 0);
      }
    cur ^= 1;
  }

  const float* bp = gubias + (size_t)e * 2 * I_;
  unsigned short* od = inter + ((size_t)e * T_ + t0) * I_ + i0;
#pragma unroll
  for (int m = 0; m < 4; ++m) {
    const int rb = wm * 64 + m * 16 + lq * 4;
#pragma unroll
    for (int n = 0; n < 4; ++n) {
      const int ic = wn * 64 + n * 16 + lr;
      const float bg_ = bp[2 * (i0 + ic)];
      const float bu_ = bp[2 * (i0 + ic) + 1];
#pragma unroll
      for (int j = 0; j < 4; ++j) {
        float g = accg[m][n][j] + bg_;
        float u = accu[m][n][j] + bu_;
        g = fminf(g, FLIMIT);
        u = fminf(fmaxf(u, -FLIMIT), FLIMIT);
        const float glu = g / (1.0f + __expf(-ALPHA_ * g));
        od[(size_t)(rb + j) * I_ + ic] = f2bf((u + 1.0f) * glu);
      }
    }
  }
}

// ---------------- GEMM2: out += r[t,e] * (inter @ down + bias) ----------------

__global__ __launch_bounds__(256, 2) void k_gemm2(
    const unsigned short* __restrict__ interp, // [E][T][I]
    const unsigned short* __restrict__ Dt,     // [E][H][I] (B^T layout)
    const float* __restrict__ dbias,           // [E][H]
    const float* __restrict__ rwt,             // [T][E]
    float* __restrict__ out)                   // [T][H] fp32, pre-zeroed
{
  const int e  = blockIdx.z;
  const int t0 = blockIdx.y * 128;
  const int h0 = blockIdx.x * 128;

  __shared__ unsigned short sA[2][128 * 32];
  __shared__ unsigned short sB[2][128 * 32];

  const int tid  = threadIdx.x;
  const int wid  = tid >> 6;
  const int lane = tid & 63;
  const int wm   = wid >> 1;
  const int wn   = wid & 1;
  const int lr   = lane & 15;
  const int lq   = lane >> 4;
  const int kch  = lq * 8;

  const unsigned short* ga = interp + ((size_t)e * T_ + t0) * I_;
  const unsigned short* gb = Dt     + ((size_t)e * H_ + h0) * I_;

  float4v acc[4][4] = {};

  auto stage = [&](int buf, int kt) {
    const int k0 = kt * 32;
#pragma unroll
    for (int it = 0; it < 2; ++it) {
      const int c = tid + it * 256;
      const int r = c >> 2;
      const size_t go = (size_t)r * I_ + (k0 + (c & 3) * 8);
      gll16(ga + go, &sA[buf][c * 8]);
      gll16(gb + go, &sB[buf][c * 8]);
    }
  };

  stage(0, 0);
  int cur = 0;
#pragma unroll 1
  for (int kt = 0; kt < 64; ++kt) {
    __syncthreads();
    if (kt + 1 < 64) stage(cur ^ 1, kt + 1);
    short8 a[4], b[4];
#pragma unroll
    for (int m = 0; m < 4; ++m)
      a[m] = *(const short8*)&sA[cur][(wm * 64 + m * 16 + lr) * 32 + kch];
#pragma unroll
    for (int n = 0; n < 4; ++n)
      b[n] = *(const short8*)&sB[cur][(wn * 64 + n * 16 + lr) * 32 + kch];
#pragma unroll
    for (int m = 0; m < 4; ++m)
#pragma unroll
      for (int n = 0; n < 4; ++n)
        acc[m][n] = __builtin_amdgcn_mfma_f32_16x16x32_bf16(a[m], b[n], acc[m][n], 0, 0, 0);
    cur ^= 1;
  }

  float rv[4][4];
#pragma unroll
  for (int m = 0; m < 4; ++m)
#pragma unroll
    for (int j = 0; j < 4; ++j)
      rv[m][j] = rwt[(size_t)(t0 + wm * 64 + m * 16 + lq * 4 + j) * E_ + e];

  const float* db = dbias + (size_t)e * H_;
#pragma unroll
  for (int m = 0; m < 4; ++m) {
    const int rb = t0 + wm * 64 + m * 16 + lq * 4;
#pragma unroll
    for (int n = 0; n < 4; ++n) {
      const int h = h0 + wn * 64 + n * 16 + lr;
      const float b_ = db[h];
#pragma unroll
      for (int j = 0; j < 4; ++j)
        atomicAdd(&out[(size_t)(rb + j) * H_ + h], rv[m][j] * (acc[m][n][j] + b_));
    }
  }
}

// ---------------- launch ----------------

extern "C" void kernel_launch(void* const* d_in, const int* in_sizes, int n_in,
                              void* d_out, int out_size, void* d_ws, size_t ws_size,
                              hipStream_t stream) {
  (void)in_sizes; (void)n_in; (void)ws_size;
  const float* hs  = (const float*)d_in[0];
  const float* rwt = (const float*)d_in[1];
  const float* gup = (const float*)d_in[2];
  const float* gub = (const float*)d_in[3];
  const float* dp  = (const float*)d_in[4];
  const float* dpb = (const float*)d_in[5];

  // workspace layout (bf16 = ushort), total ~264 MiB
  unsigned short* hid = (unsigned short*)d_ws;
  unsigned short* wg  = hid + (size_t)T_ * H_;
  unsigned short* wu  = wg  + (size_t)E_ * I_ * H_;
  unsigned short* dt  = wu  + (size_t)E_ * I_ * H_;
  unsigned short* itr = dt  + (size_t)E_ * I_ * H_;

  hipMemsetAsync(d_out, 0, (size_t)out_size * sizeof(float), stream);
  k_cvt_hidden<<<T_ * H_ / 1024, 256, 0, stream>>>(hs, hid);
  k_cvt_gateup<<<dim3(I_ / 64, H_ / 64, E_), 256, 0, stream>>>(gup, wg, wu);
  k_cvt_down<<<dim3(H_ / 64, I_ / 64, E_), 256, 0, stream>>>(dp, dt);
  k_gemm1<<<dim3(I_ / 128, T_ / 128, E_), 256, 0, stream>>>(hid, wg, wu, gub, itr);
  k_gemm2<<<dim3(H_ / 128, T_ / 128, E_), 256, 0, stream>>>(itr, dt, dpb, rwt, (float*)d_out);
}